// Round 7
// baseline (239.791 us; speedup 1.0000x reference)
//
#include <hip/hip_runtime.h>
#include <hip/hip_bf16.h>
#include <cmath>

typedef __bf16 bf16;
typedef __bf16 bf16x8 __attribute__((ext_vector_type(8)));
typedef __bf16 bf16x4v __attribute__((ext_vector_type(4)));
typedef float f32x4 __attribute__((ext_vector_type(4)));

#define B_ 4
#define T_ 2048
#define C_ 1024
#define H_ 16
#define D_ 64
#define BT_ 8192
#define LOG2E 1.4426950408889634f

// ---------- helpers ----------
__device__ __forceinline__ void async_cp16(const void* g, void* l) {
  __builtin_amdgcn_global_load_lds(
      (__attribute__((address_space(1))) void*)g,
      (__attribute__((address_space(3))) void*)l, 16, 0, 0);
}

__device__ __forceinline__ f32x4 mfma16(bf16x8 a, bf16x8 b, f32x4 c) {
  return __builtin_amdgcn_mfma_f32_16x16x32_bf16(a, b, c, 0, 0, 0);
}

// ---------- prep: cast x (blocks 0..8191) + 4 weight transposes ----------
__global__ __launch_bounds__(256) void prep_kernel(
    const float* __restrict__ x, const float* __restrict__ Wq,
    const float* __restrict__ Wk, const float* __restrict__ Wv,
    const float* __restrict__ Wo, bf16* __restrict__ xb,
    bf16* __restrict__ wt) {
  __shared__ float tile[32][33];
  const int id = blockIdx.x;
  const int t = threadIdx.x;
  if (id < 8192) {
    const int i = id * 256 + t;
    float4 v = ((const float4*)x)[i];
    bf16x4v o = {(bf16)v.x, (bf16)v.y, (bf16)v.z, (bf16)v.w};
    ((bf16x4v*)xb)[i] = o;
    return;
  }
  const int id2 = id - 8192;
  const int z = id2 >> 10;
  const float* W = (z == 0) ? Wq : (z == 1) ? Wk : (z == 2) ? Wv : Wo;
  bf16* Wt = wt + (size_t)z * 1048576;
  const int bx = id2 & 31, by = (id2 >> 5) & 31;
  const int xx = t & 31, yy = t >> 5;  // 32 x 8
  const int n0 = bx * 32, k0 = by * 32;
#pragma unroll
  for (int j = 0; j < 32; j += 8)
    tile[yy + j][xx] = W[(size_t)(k0 + yy + j) * C_ + n0 + xx];
  __syncthreads();
#pragma unroll
  for (int j = 0; j < 32; j += 8)
    Wt[(size_t)(n0 + yy + j) * C_ + k0 + xx] = (bf16)tile[xx][yy + j];
}

// ---------- GEMM tile: BK=32 double-buffered prefetch-after-barrier ----------
// C[m][n] = sum_k A[m][k]*Bt[n][k]. Per-tensor buffer = 128x32 = 8KB, dbuf
// -> 32KB total -> 4 blocks/CU (16 waves) with __launch_bounds__(256,4).
// Read swizzle: phys chunk = quad ^ (row&3) -> 8 banks x 2 lanes (free).
// Staging: thread t covers row t>>2 (+64), fetches logical chunk
// (t&3)^(row&3) into phys chunk t&3 (LDS linear t*16B).
template <int F32OUT>
__device__ __forceinline__ void gemm_tile_db(
    const bf16* __restrict__ A, const bf16* __restrict__ Bt,
    void* __restrict__ Cv, const float* __restrict__ bias, int M, int N, int K,
    int m0, int n0, bf16* As, bf16* Bs) {
  const int t = threadIdx.x;
  const int lane = t & 63;
  const int wave = t >> 6;
  const int quad = lane >> 4;
  const int l15 = lane & 15;
  const int wm = (wave >> 1) * 64;
  const int wn = (wave & 1) * 64;

  // staging: row = t>>2 (0..63, +64 for second cp16), logical chunk
  const int srow = t >> 2;
  const int sc0 = (t & 3) ^ (srow & 3);
  const bf16* Ag = A + (size_t)(m0 + srow) * K + sc0 * 8;
  const bf16* Ag2 = A + (size_t)(m0 + 64 + srow) * K + sc0 * 8;  // row+64: same &3
  const bf16* Bg = Bt + (size_t)(n0 + srow) * K + sc0 * 8;
  const bf16* Bg2 = Bt + (size_t)(n0 + 64 + srow) * K + sc0 * 8;

  const int niter = K >> 5;
  auto stage = [&](int kt, int buf) {
    bf16* Ad = As + buf * 4096 + t * 8;
    bf16* Bd = Bs + buf * 4096 + t * 8;
    async_cp16(Ag + kt * 32, Ad);
    async_cp16(Ag2 + kt * 32, Ad + 2048);
    async_cp16(Bg + kt * 32, Bd);
    async_cp16(Bg2 + kt * 32, Bd + 2048);
  };

  f32x4 acc[4][4] = {};
  stage(0, 0);

  for (int kt = 0; kt < niter; kt++) {
    __syncthreads();  // drains stage(kt), issued one compute phase ago
    if (kt + 1 < niter) stage(kt + 1, (kt + 1) & 1);
    const bf16* Ab = As + (kt & 1) * 4096;
    const bf16* Bb = Bs + (kt & 1) * 4096;
    bf16x8 af[4], bfr[4];
#pragma unroll
    for (int i = 0; i < 4; i++) {
      const int r = wm + i * 16 + l15;
      af[i] = *(const bf16x8*)&Ab[r * 32 + ((quad ^ (r & 3)) * 8)];
    }
#pragma unroll
    for (int j = 0; j < 4; j++) {
      const int r = wn + j * 16 + l15;
      bfr[j] = *(const bf16x8*)&Bb[r * 32 + ((quad ^ (r & 3)) * 8)];
    }
#pragma unroll
    for (int i = 0; i < 4; i++)
#pragma unroll
      for (int j = 0; j < 4; j++)
        acc[i][j] = mfma16(af[i], bfr[j], acc[i][j]);
  }

  // epilogue: C/D layout col = lane&15, row = quad*4 + r  [verified m89/m91]
#pragma unroll
  for (int i = 0; i < 4; i++) {
    const int gr = m0 + wm + i * 16 + quad * 4;
#pragma unroll
    for (int j = 0; j < 4; j++) {
      const int gc = n0 + wn + j * 16 + l15;
      const float bv = F32OUT ? bias[gc] : 0.0f;
#pragma unroll
      for (int r = 0; r < 4; r++) {
        const float v = acc[i][j][r] + bv;
        if (F32OUT)
          ((float*)Cv)[(size_t)(gr + r) * N + gc] = v;
        else
          ((bf16*)Cv)[(size_t)(gr + r) * N + gc] = (bf16)v;
      }
    }
  }
}

// ---------- fused QK-projection + V^T-projection ----------
// blocks 0..1023: qkb[8192][2048] = xb @ wqkT   (m-tile id>>4, n-tile id&15)
// blocks 1024..1535: vtb[1024][8192] = wvT @ xb^T (m-tile id>>6, n-tile id&63)
__global__ __launch_bounds__(256, 4) void qkv_gemm_kernel(
    const bf16* __restrict__ xb, const bf16* __restrict__ wqkvT,
    bf16* __restrict__ qkb, bf16* __restrict__ vtb) {
  __shared__ __align__(16) bf16 As[2 * 4096];
  __shared__ __align__(16) bf16 Bs[2 * 4096];
  int id = blockIdx.x;
  if (id < 1024) {
    gemm_tile_db<0>(xb, wqkvT, (void*)qkb, nullptr, 8192, 2048, 1024,
                    (id >> 4) * 128, (id & 15) * 128, As, Bs);
  } else {
    id -= 1024;
    gemm_tile_db<0>(wqkvT + 2 * 1024 * 1024, xb, (void*)vtb, nullptr, 1024,
                    8192, 1024, (id >> 6) * 128, (id & 63) * 128, As, Bs);
  }
}

// ---------- output projection + bias ----------
__global__ __launch_bounds__(256, 4) void out_gemm_kernel(
    const bf16* __restrict__ attn, const bf16* __restrict__ woT,
    float* __restrict__ out, const float* __restrict__ bo) {
  __shared__ __align__(16) bf16 As[2 * 4096];
  __shared__ __align__(16) bf16 Bs[2 * 4096];
  const int id = blockIdx.x;
  gemm_tile_db<1>(attn, woT, (void*)out, bo, 8192, 1024, 1024,
                  (id >> 3) * 128, (id & 7) * 128, As, Bs);
}

// ---------- causal flash attention v5 ----------
// S^T = K Q^T, O^T = V^T P; no-max softmax (scores bounded ~|7|); LOG2E folded
// into Q pre-scale. Prefetch-after-barrier double-buffered Ks/Vs (64-k
// sub-tiles); Ps stride 72 (conflict-free). LDS 50KB -> 3 blocks/CU.
__global__ __launch_bounds__(256, 3) void flash_attn_kernel(
    const bf16* __restrict__ qk, const bf16* __restrict__ vt,
    bf16* __restrict__ attn) {
  __shared__ __align__(16) char smem[51200];
  bf16* KsB = (bf16*)smem;            // [2][4096] elems (2 x 8KB)
  bf16* VsB = (bf16*)(smem + 16384);  // [2][4096] elems
  bf16* Ps = (bf16*)(smem + 32768);   // [128][72]

  const int t = threadIdx.x;
  const int lane = t & 63;
  const int wave = t >> 6;
  const int quad = lane >> 4;
  const int l15 = lane & 15;
  const int l7 = l15 & 7;
  const int bx = blockIdx.x;
  const int qt = 15 - (bx >> 6);  // heavy tiles dispatched first
  const int bh = bx & 63;
  const int b = bh >> 4;
  const int h = bh & 15;

  const bf16* Qg = qk + (size_t)b * T_ * 2048 + h * 64;
  const bf16* Kg = qk + (size_t)b * T_ * 2048 + 1024 + h * 64;
  const bf16* Vg = vt + (size_t)h * 64 * BT_ + b * T_;

  // Q fragments (B-operand), pre-scaled by LOG2E/8
  const float QSCALE = 0.125f * LOG2E;
  bf16x8 qf[2][2];
  const int qrow0 = qt * 128 + wave * 32;
#pragma unroll
  for (int mt = 0; mt < 2; mt++)
#pragma unroll
    for (int ks = 0; ks < 2; ks++) {
      bf16x8 v = *(const bf16x8*)(Qg + (size_t)(qrow0 + mt * 16 + l15) * 2048 +
                                  ks * 32 + quad * 8);
#pragma unroll
      for (int j = 0; j < 8; j++) v[j] = (bf16)((float)v[j] * QSCALE);
      qf[mt][ks] = v;
    }

  f32x4 o_acc[4][2] = {};  // O^T frags: [dt][mt]
  f32x4 l4[2] = {};        // per-lane partial softmax denominators

  const int sr8 = lane >> 3;
  const int sc = (lane & 7) ^ sr8;

  auto stage = [&](int j64, int buf) {
    const int k0 = j64 * 64;
    bf16* KL = KsB + buf * 4096 + wave * 1024 + lane * 8;
    const bf16* KG = Kg + (size_t)(k0 + wave * 16 + sr8) * 2048 + sc * 8;
    async_cp16(KG, KL);
    async_cp16(KG + (size_t)8 * 2048, KL + 512);
    bf16* VL = VsB + buf * 4096 + wave * 1024 + lane * 8;
    const bf16* VG = Vg + (size_t)(wave * 16 + sr8) * BT_ + k0 + sc * 8;
    async_cp16(VG, VL);
    async_cp16(VG + (size_t)8 * BT_, VL + 512);
  };

  const int S = 2 * qt + 2;
  stage(0, 0);

  for (int s = 0; s < S; s++) {
    __syncthreads();  // drains stage(s) (issued one compute phase ago)
    if (s + 1 < S) stage(s + 1, (s + 1) & 1);
    const bf16* Kb = KsB + (s & 1) * 4096;
    const bf16* Vb = VsB + (s & 1) * 4096;
    const int k0 = s * 64;
    const bool diag = (s >= 2 * qt);

    // ---- S^T = K Q^T (pre-scaled), mask, exp2, l-accumulate, pack ----
    bf16x4v p[2][4];
#pragma unroll
    for (int kt = 0; kt < 4; kt++) {
      const bf16x8 kf0 =
          *(const bf16x8*)&Kb[(kt * 16 + l15) * 64 + ((quad ^ l7) * 8)];
      const bf16x8 kf1 =
          *(const bf16x8*)&Kb[(kt * 16 + l15) * 64 + (((4 + quad) ^ l7) * 8)];
#pragma unroll
      for (int mt = 0; mt < 2; mt++) {
        f32x4 sv = mfma16(kf0, qf[mt][0], f32x4{0.f, 0.f, 0.f, 0.f});
        sv = mfma16(kf1, qf[mt][1], sv);
        if (diag) {
          const int qg = qt * 128 + wave * 32 + mt * 16 + l15;
#pragma unroll
          for (int i = 0; i < 4; i++)
            if (k0 + kt * 16 + quad * 4 + i > qg) sv[i] = -INFINITY;
        }
        f32x4 e;
#pragma unroll
        for (int i = 0; i < 4; i++) e[i] = __builtin_amdgcn_exp2f(sv[i]);
        l4[mt] += e;
        p[mt][kt] = bf16x4v{(bf16)e[0], (bf16)e[1], (bf16)e[2], (bf16)e[3]};
      }
    }

    // ---- P -> LDS (wave-private rows, stride 72: conflict-free) ----
#pragma unroll
    for (int mt = 0; mt < 2; mt++) {
      const int row = wave * 32 + mt * 16 + l15;
#pragma unroll
      for (int kt = 0; kt < 4; kt++)
        *(bf16x4v*)&Ps[row * 72 + kt * 16 + quad * 4] = p[mt][kt];
    }

    // ---- O^T += V^T P ----
#pragma unroll
    for (int ks2 = 0; ks2 < 2; ks2++) {
      bf16x8 pa[2], vb[4];
#pragma unroll
      for (int mt = 0; mt < 2; mt++)
        pa[mt] = *(const bf16x8*)&Ps[(wave * 32 + mt * 16 + l15) * 72 +
                                     ks2 * 32 + quad * 8];
#pragma unroll
      for (int dt = 0; dt < 4; dt++)
        vb[dt] = *(const bf16x8*)&Vb[(dt * 16 + l15) * 64 +
                                     (((ks2 * 4 + quad) ^ l7) * 8)];
#pragma unroll
      for (int dt = 0; dt < 4; dt++)
#pragma unroll
        for (int mt = 0; mt < 2; mt++)
          o_acc[dt][mt] = mfma16(vb[dt], pa[mt], o_acc[dt][mt]);
    }
  }

  // ---- epilogue: l reduce over quads, normalize, 8B stores ----
  float inv[2];
#pragma unroll
  for (int mt = 0; mt < 2; mt++) {
    float l = l4[mt][0] + l4[mt][1] + l4[mt][2] + l4[mt][3];
    l += __shfl_xor(l, 16, 64);
    l += __shfl_xor(l, 32, 64);
    inv[mt] = 1.0f / l;
  }
#pragma unroll
  for (int dt = 0; dt < 4; dt++)
#pragma unroll
    for (int mt = 0; mt < 2; mt++) {
      const int q = qt * 128 + wave * 32 + mt * 16 + l15;
      bf16x4v o = {(bf16)(o_acc[dt][mt][0] * inv[mt]),
                   (bf16)(o_acc[dt][mt][1] * inv[mt]),
                   (bf16)(o_acc[dt][mt][2] * inv[mt]),
                   (bf16)(o_acc[dt][mt][3] * inv[mt])};
      *(bf16x4v*)(attn + (size_t)(b * T_ + q) * 1024 + h * 64 + dt * 16 +
                  quad * 4) = o;
    }
}

// ---------- host ----------
extern "C" void kernel_launch(void* const* d_in, const int* in_sizes, int n_in,
                              void* d_out, int out_size, void* d_ws,
                              size_t ws_size, hipStream_t stream) {
  const float* x = (const float*)d_in[0];
  const float* Wq = (const float*)d_in[1];
  const float* Wk = (const float*)d_in[2];
  const float* Wv = (const float*)d_in[3];
  const float* Wo = (const float*)d_in[4];
  const float* bo = (const float*)d_in[5];
  float* out = (float*)d_out;

  char* ws = (char*)d_ws;
  // workspace layout (bytes): total 92 MB
  bf16* xb = (bf16*)(ws);              // [8192][1024]   16 MB
  bf16* qkb = (bf16*)(ws + 16777216);  // [8192][2048]   32 MB
  bf16* vtb = (bf16*)(ws + 50331648);  // [1024][8192]   16 MB
  bf16* attn = (bf16*)(ws + 67108864); // [8192][1024]   16 MB
  bf16* wqkvT = (bf16*)(ws + 83886080);// [4096][1024]    8 MB (q,k,v,o)

  // prep: cast x (8192 blocks) + 4 weight transposes (4096 blocks)
  prep_kernel<<<12288, 256, 0, stream>>>(x, Wq, Wk, Wv, Wo, xb, wqkvT);

  // fused QK projection (1024 blocks) + V^T projection (512 blocks)
  qkv_gemm_kernel<<<1536, 256, 0, stream>>>(xb, wqkvT, qkb, vtb);

  // causal flash attention -> attn [8192][1024] bf16
  flash_attn_kernel<<<1024, 256, 0, stream>>>(qkb, vtb, attn);

  // output projection + bias: [8192,1024] @ [1024,1024] -> out fp32
  out_gemm_kernel<<<512, 256, 0, stream>>>(attn, wqkvT + 3 * 1024 * 1024, out,
                                           bo);
}

// Round 8
// 234.959 us; speedup vs baseline: 1.0206x; 1.0206x over previous
//
#include <hip/hip_runtime.h>
#include <hip/hip_bf16.h>
#include <cmath>

typedef __bf16 bf16;
typedef __bf16 bf16x8 __attribute__((ext_vector_type(8)));
typedef __bf16 bf16x4v __attribute__((ext_vector_type(4)));
typedef float f32x4 __attribute__((ext_vector_type(4)));

#define B_ 4
#define T_ 2048
#define C_ 1024
#define H_ 16
#define D_ 64
#define BT_ 8192
#define LOG2E 1.4426950408889634f

// ---------- helpers ----------
__device__ __forceinline__ void async_cp16(const void* g, void* l) {
  __builtin_amdgcn_global_load_lds(
      (__attribute__((address_space(1))) void*)g,
      (__attribute__((address_space(3))) void*)l, 16, 0, 0);
}

__device__ __forceinline__ f32x4 mfma16(bf16x8 a, bf16x8 b, f32x4 c) {
  return __builtin_amdgcn_mfma_f32_16x16x32_bf16(a, b, c, 0, 0, 0);
}

// ---------- prep: cast x (blocks 0..8191) + 4 weight transposes ----------
__global__ __launch_bounds__(256) void prep_kernel(
    const float* __restrict__ x, const float* __restrict__ Wq,
    const float* __restrict__ Wk, const float* __restrict__ Wv,
    const float* __restrict__ Wo, bf16* __restrict__ xb,
    bf16* __restrict__ wt) {
  __shared__ float tile[32][33];
  const int id = blockIdx.x;
  const int t = threadIdx.x;
  if (id < 8192) {
    const int i = id * 256 + t;
    float4 v = ((const float4*)x)[i];
    bf16x4v o = {(bf16)v.x, (bf16)v.y, (bf16)v.z, (bf16)v.w};
    ((bf16x4v*)xb)[i] = o;
    return;
  }
  const int id2 = id - 8192;
  const int z = id2 >> 10;
  const float* W = (z == 0) ? Wq : (z == 1) ? Wk : (z == 2) ? Wv : Wo;
  bf16* Wt = wt + (size_t)z * 1048576;
  const int bx = id2 & 31, by = (id2 >> 5) & 31;
  const int xx = t & 31, yy = t >> 5;  // 32 x 8
  const int n0 = bx * 32, k0 = by * 32;
#pragma unroll
  for (int j = 0; j < 32; j += 8)
    tile[yy + j][xx] = W[(size_t)(k0 + yy + j) * C_ + n0 + xx];
  __syncthreads();
#pragma unroll
  for (int j = 0; j < 32; j += 8)
    Wt[(size_t)(n0 + yy + j) * C_ + k0 + xx] = (bf16)tile[xx][yy + j];
}

// ---------- GEMM tile: BK=32 dbuf, line-packed conflict-free LDS ----------
// C[m][n] = sum_k A[m][k]*Bt[n][k]. Per-tensor buffer 8KB, dbuf -> 32KB
// -> 4 blocks/CU.  LDS layout: line L (64 elems, 128B) holds rows L and
// L+64, split into 8 slots of 8 elems; logical (half h=row>>6, k-chunk c)
// sits at phys slot p = (h*4+c) ^ (L&7).  Reads: bank-start = 4p, 8 slots
// x 2 lanes per 16-lane phase = 2-way = free.  Staging stays lane-linear
// (thread t -> line t>>3 [+32], slot t&7), cp16-compatible; thread t
// fetches global (row, chunk) = invert(p=t&7, L=t>>3).
template <int F32OUT>
__device__ __forceinline__ void gemm_tile_db(
    const bf16* __restrict__ A, const bf16* __restrict__ Bt,
    void* __restrict__ Cv, const float* __restrict__ bias, int M, int N, int K,
    int m0, int n0, bf16* As, bf16* Bs) {
  const int t = threadIdx.x;
  const int lane = t & 63;
  const int wave = t >> 6;
  const int quad = lane >> 4;
  const int l15 = lane & 15;
  const int wm = (wave >> 1) * 64;
  const int wn = (wave & 1) * 64;

  // staging map: u = slot ^ (line&7) encodes (h, c); row = line + 64h.
  // second cp16 covers line+32 (32 = 0 mod 8 -> same u).
  const int u = (t & 7) ^ ((t >> 3) & 7);
  const int sh = u >> 2;
  const int scx = u & 3;
  const int r0 = (t >> 3) + 64 * sh;
  const bf16* Ag = A + (size_t)(m0 + r0) * K + scx * 8;
  const bf16* Ag2 = A + (size_t)(m0 + r0 + 32) * K + scx * 8;
  const bf16* Bg = Bt + (size_t)(n0 + r0) * K + scx * 8;
  const bf16* Bg2 = Bt + (size_t)(n0 + r0 + 32) * K + scx * 8;

  const int niter = K >> 5;
  auto stage = [&](int kt, int buf) {
    bf16* Ad = As + buf * 4096 + t * 8;
    bf16* Bd = Bs + buf * 4096 + t * 8;
    async_cp16(Ag + kt * 32, Ad);
    async_cp16(Ag2 + kt * 32, Ad + 2048);
    async_cp16(Bg + kt * 32, Bd);
    async_cp16(Bg2 + kt * 32, Bd + 2048);
  };

  f32x4 acc[4][4] = {};
  stage(0, 0);

  for (int kt = 0; kt < niter; kt++) {
    __syncthreads();  // drains stage(kt), issued one compute phase ago
    if (kt + 1 < niter) stage(kt + 1, (kt + 1) & 1);
    const bf16* Ab = As + (kt & 1) * 4096;
    const bf16* Bb = Bs + (kt & 1) * 4096;
    bf16x8 af[4], bfr[4];
#pragma unroll
    for (int i = 0; i < 4; i++) {
      const int r = wm + i * 16 + l15;
      const int L = r & 63;
      af[i] = *(const bf16x8*)
          &Ab[L * 64 + ((((r >> 6) * 4 + quad) ^ (L & 7)) * 8)];
    }
#pragma unroll
    for (int j = 0; j < 4; j++) {
      const int r = wn + j * 16 + l15;
      const int L = r & 63;
      bfr[j] = *(const bf16x8*)
          &Bb[L * 64 + ((((r >> 6) * 4 + quad) ^ (L & 7)) * 8)];
    }
#pragma unroll
    for (int i = 0; i < 4; i++)
#pragma unroll
      for (int j = 0; j < 4; j++)
        acc[i][j] = mfma16(af[i], bfr[j], acc[i][j]);
  }

  // epilogue: C/D layout col = lane&15, row = quad*4 + r  [verified m89/m91]
#pragma unroll
  for (int i = 0; i < 4; i++) {
    const int gr = m0 + wm + i * 16 + quad * 4;
#pragma unroll
    for (int j = 0; j < 4; j++) {
      const int gc = n0 + wn + j * 16 + l15;
      const float bv = F32OUT ? bias[gc] : 0.0f;
#pragma unroll
      for (int r = 0; r < 4; r++) {
        const float v = acc[i][j][r] + bv;
        if (F32OUT)
          ((float*)Cv)[(size_t)(gr + r) * N + gc] = v;
        else
          ((bf16*)Cv)[(size_t)(gr + r) * N + gc] = (bf16)v;
      }
    }
  }
}

// ---------- fused QK-projection + V^T-projection, XCD-aware remap ----------
// HW maps block->XCD round-robin (id%8).  QK (64m x 16n tiles): XCD owns an
// n-pair -> B-slice 512KB L2-resident, A-tile reused by both n's.
// VT (8m x 64n): XCD owns 8 n-tiles -> B-slice 2MB + A 2MB, fits 4MB L2.
__global__ __launch_bounds__(256, 4) void qkv_gemm_kernel(
    const bf16* __restrict__ xb, const bf16* __restrict__ wqkvT,
    bf16* __restrict__ qkb, bf16* __restrict__ vtb) {
  __shared__ __align__(16) bf16 As[2 * 4096];
  __shared__ __align__(16) bf16 Bs[2 * 4096];
  int id = blockIdx.x;
  if (id < 1024) {
    const int xcd = id & 7, rest = id >> 3;  // rest = mt*2 + (nt&1)
    const int mt = rest >> 1;
    const int nt = xcd * 2 + (rest & 1);
    gemm_tile_db<0>(xb, wqkvT, (void*)qkb, nullptr, 8192, 2048, 1024, mt * 128,
                    nt * 128, As, Bs);
  } else {
    id -= 1024;  // 1024 = 0 mod 8: XCD alignment preserved
    const int xcd = id & 7, rest = id >> 3;  // rest = mt*8 + (nt&7)
    const int mt = rest >> 3;
    const int nt = xcd * 8 + (rest & 7);
    gemm_tile_db<0>(wqkvT + 2 * 1024 * 1024, xb, (void*)vtb, nullptr, 1024,
                    8192, 1024, mt * 128, nt * 128, As, Bs);
  }
}

// ---------- output projection + bias, XCD-aware (m-slice per XCD) ----------
__global__ __launch_bounds__(256, 4) void out_gemm_kernel(
    const bf16* __restrict__ attn, const bf16* __restrict__ woT,
    float* __restrict__ out, const float* __restrict__ bo) {
  __shared__ __align__(16) bf16 As[2 * 4096];
  __shared__ __align__(16) bf16 Bs[2 * 4096];
  const int id = blockIdx.x;
  const int xcd = id & 7, rest = id >> 3;  // rest = nt + (mt>>3)*8
  const int nt = rest & 7;
  const int mt = xcd + (rest >> 3) * 8;  // A-slice 2MB + B 2MB per XCD
  gemm_tile_db<1>(attn, woT, (void*)out, bo, 8192, 1024, 1024, mt * 128,
                  nt * 128, As, Bs);
}

// ---------- causal flash attention v5 (unchanged from r7) ----------
__global__ __launch_bounds__(256, 3) void flash_attn_kernel(
    const bf16* __restrict__ qk, const bf16* __restrict__ vt,
    bf16* __restrict__ attn) {
  __shared__ __align__(16) char smem[51200];
  bf16* KsB = (bf16*)smem;            // [2][4096] elems (2 x 8KB)
  bf16* VsB = (bf16*)(smem + 16384);  // [2][4096] elems
  bf16* Ps = (bf16*)(smem + 32768);   // [128][72]

  const int t = threadIdx.x;
  const int lane = t & 63;
  const int wave = t >> 6;
  const int quad = lane >> 4;
  const int l15 = lane & 15;
  const int l7 = l15 & 7;
  const int bx = blockIdx.x;
  const int qt = 15 - (bx >> 6);  // heavy tiles dispatched first
  const int bh = bx & 63;         // bh%8 = XCD -> same (b,h) shares L2 K/V
  const int b = bh >> 4;
  const int h = bh & 15;

  const bf16* Qg = qk + (size_t)b * T_ * 2048 + h * 64;
  const bf16* Kg = qk + (size_t)b * T_ * 2048 + 1024 + h * 64;
  const bf16* Vg = vt + (size_t)h * 64 * BT_ + b * T_;

  const float QSCALE = 0.125f * LOG2E;
  bf16x8 qf[2][2];
  const int qrow0 = qt * 128 + wave * 32;
#pragma unroll
  for (int mt = 0; mt < 2; mt++)
#pragma unroll
    for (int ks = 0; ks < 2; ks++) {
      bf16x8 v = *(const bf16x8*)(Qg + (size_t)(qrow0 + mt * 16 + l15) * 2048 +
                                  ks * 32 + quad * 8);
#pragma unroll
      for (int j = 0; j < 8; j++) v[j] = (bf16)((float)v[j] * QSCALE);
      qf[mt][ks] = v;
    }

  f32x4 o_acc[4][2] = {};
  f32x4 l4[2] = {};

  const int sr8 = lane >> 3;
  const int sc = (lane & 7) ^ sr8;

  auto stage = [&](int j64, int buf) {
    const int k0 = j64 * 64;
    bf16* KL = KsB + buf * 4096 + wave * 1024 + lane * 8;
    const bf16* KG = Kg + (size_t)(k0 + wave * 16 + sr8) * 2048 + sc * 8;
    async_cp16(KG, KL);
    async_cp16(KG + (size_t)8 * 2048, KL + 512);
    bf16* VL = VsB + buf * 4096 + wave * 1024 + lane * 8;
    const bf16* VG = Vg + (size_t)(wave * 16 + sr8) * BT_ + k0 + sc * 8;
    async_cp16(VG, VL);
    async_cp16(VG + (size_t)8 * BT_, VL + 512);
  };

  const int S = 2 * qt + 2;
  stage(0, 0);

  for (int s = 0; s < S; s++) {
    __syncthreads();
    if (s + 1 < S) stage(s + 1, (s + 1) & 1);
    const bf16* Kb = KsB + (s & 1) * 4096;
    const bf16* Vb = VsB + (s & 1) * 4096;
    const int k0 = s * 64;
    const bool diag = (s >= 2 * qt);

    bf16x4v p[2][4];
#pragma unroll
    for (int kt = 0; kt < 4; kt++) {
      const bf16x8 kf0 =
          *(const bf16x8*)&Kb[(kt * 16 + l15) * 64 + ((quad ^ l7) * 8)];
      const bf16x8 kf1 =
          *(const bf16x8*)&Kb[(kt * 16 + l15) * 64 + (((4 + quad) ^ l7) * 8)];
#pragma unroll
      for (int mt = 0; mt < 2; mt++) {
        f32x4 sv = mfma16(kf0, qf[mt][0], f32x4{0.f, 0.f, 0.f, 0.f});
        sv = mfma16(kf1, qf[mt][1], sv);
        if (diag) {
          const int qg = qt * 128 + wave * 32 + mt * 16 + l15;
#pragma unroll
          for (int i = 0; i < 4; i++)
            if (k0 + kt * 16 + quad * 4 + i > qg) sv[i] = -INFINITY;
        }
        f32x4 e;
#pragma unroll
        for (int i = 0; i < 4; i++) e[i] = __builtin_amdgcn_exp2f(sv[i]);
        l4[mt] += e;
        p[mt][kt] = bf16x4v{(bf16)e[0], (bf16)e[1], (bf16)e[2], (bf16)e[3]};
      }
    }

#pragma unroll
    for (int mt = 0; mt < 2; mt++) {
      const int row = wave * 32 + mt * 16 + l15;
#pragma unroll
      for (int kt = 0; kt < 4; kt++)
        *(bf16x4v*)&Ps[row * 72 + kt * 16 + quad * 4] = p[mt][kt];
    }

#pragma unroll
    for (int ks2 = 0; ks2 < 2; ks2++) {
      bf16x8 pa[2], vb[4];
#pragma unroll
      for (int mt = 0; mt < 2; mt++)
        pa[mt] = *(const bf16x8*)&Ps[(wave * 32 + mt * 16 + l15) * 72 +
                                     ks2 * 32 + quad * 8];
#pragma unroll
      for (int dt = 0; dt < 4; dt++)
        vb[dt] = *(const bf16x8*)&Vb[(dt * 16 + l15) * 64 +
                                     (((ks2 * 4 + quad) ^ l7) * 8)];
#pragma unroll
      for (int dt = 0; dt < 4; dt++)
#pragma unroll
        for (int mt = 0; mt < 2; mt++)
          o_acc[dt][mt] = mfma16(vb[dt], pa[mt], o_acc[dt][mt]);
    }
  }

  float inv[2];
#pragma unroll
  for (int mt = 0; mt < 2; mt++) {
    float l = l4[mt][0] + l4[mt][1] + l4[mt][2] + l4[mt][3];
    l += __shfl_xor(l, 16, 64);
    l += __shfl_xor(l, 32, 64);
    inv[mt] = 1.0f / l;
  }
#pragma unroll
  for (int dt = 0; dt < 4; dt++)
#pragma unroll
    for (int mt = 0; mt < 2; mt++) {
      const int q = qt * 128 + wave * 32 + mt * 16 + l15;
      bf16x4v o = {(bf16)(o_acc[dt][mt][0] * inv[mt]),
                   (bf16)(o_acc[dt][mt][1] * inv[mt]),
                   (bf16)(o_acc[dt][mt][2] * inv[mt]),
                   (bf16)(o_acc[dt][mt][3] * inv[mt])};
      *(bf16x4v*)(attn + (size_t)(b * T_ + q) * 1024 + h * 64 + dt * 16 +
                  quad * 4) = o;
    }
}

// ---------- host ----------
extern "C" void kernel_launch(void* const* d_in, const int* in_sizes, int n_in,
                              void* d_out, int out_size, void* d_ws,
                              size_t ws_size, hipStream_t stream) {
  const float* x = (const float*)d_in[0];
  const float* Wq = (const float*)d_in[1];
  const float* Wk = (const float*)d_in[2];
  const float* Wv = (const float*)d_in[3];
  const float* Wo = (const float*)d_in[4];
  const float* bo = (const float*)d_in[5];
  float* out = (float*)d_out;

  char* ws = (char*)d_ws;
  bf16* xb = (bf16*)(ws);               // [8192][1024]   16 MB
  bf16* qkb = (bf16*)(ws + 16777216);   // [8192][2048]   32 MB
  bf16* vtb = (bf16*)(ws + 50331648);   // [1024][8192]   16 MB
  bf16* attn = (bf16*)(ws + 67108864);  // [8192][1024]   16 MB
  bf16* wqkvT = (bf16*)(ws + 83886080); // [4096][1024]    8 MB (q,k,v,o)

  prep_kernel<<<12288, 256, 0, stream>>>(x, Wq, Wk, Wv, Wo, xb, wqkvT);

  qkv_gemm_kernel<<<1536, 256, 0, stream>>>(xb, wqkvT, qkb, vtb);

  flash_attn_kernel<<<1024, 256, 0, stream>>>(qkb, vtb, attn);

  out_gemm_kernel<<<512, 256, 0, stream>>>(attn, wqkvT + 3 * 1024 * 1024, out,
                                           bo);
}